// Round 13
// baseline (277.952 us; speedup 1.0000x reference)
//
#include <hip/hip_runtime.h>
#include <hip/hip_bf16.h>
#include <hip/hip_fp16.h>

#define NEG_SLOPE 0.2f
#define NBUCK_MAX 256   // buckets of 512 nodes; 100k nodes -> 196 buckets
#define BCAP 12288      // fixed bucket capacity (mean 8163, sigma ~90 -> 45 sigma slack)
#define TILE 2048       // edges per binA block (8 per thread)

typedef float v2f __attribute__((ext_vector_type(2)));

__device__ __forceinline__ float lrelu(float v) { return v >= 0.f ? v : NEG_SLOPE * v; }

__device__ __forceinline__ float wave_sum(float v) {
    for (int o = 32; o; o >>= 1) v += __shfl_down(v, o, 64);
    return v;
}

__device__ __forceinline__ void h8_to_f(const uint4 v, float* f) {
    float2 a = __half22float2(*(const __half2*)&v.x);
    float2 b = __half22float2(*(const __half2*)&v.y);
    float2 c = __half22float2(*(const __half2*)&v.z);
    float2 d = __half22float2(*(const __half2*)&v.w);
    f[0] = a.x; f[1] = a.y; f[2] = b.x; f[3] = b.y;
    f[4] = c.x; f[5] = c.y; f[6] = d.x; f[7] = d.y;
}

// ce1[h] = dot(We1[h*64..], ae1[h*64..]) — wave h computes head h. 256 threads.
__device__ __forceinline__ void compute_ce1(const float* __restrict__ We1,
                                            const float* __restrict__ ae1,
                                            float* ce /*shared[4]*/) {
    int t = threadIdx.x;
    float p = wave_sum(We1[t] * ae1[t]);
    if ((t & 63) == 0) ce[t >> 6] = p;
    __syncthreads();
}

__device__ __forceinline__ float compute_ce2(const float* __restrict__ We2,
                                             const float* __restrict__ ae2,
                                             float* sh /*shared[1]*/) {
    int t = threadIdx.x;
    if (t < 64) {
        float p = wave_sum(We2[t] * ae2[t]);
        if (t == 0) sh[0] = p;
    }
    __syncthreads();
    return sh[0];
}

// ---------------- Layer-1 prep: node rec {al_s1[4],x0,x1}; al_d1; zero deg; folded V --
// V layout (global): [0..255]=V0W, [256..511]=V1W, [512..575]=cW, [576..639]=cb2,
// [640..643]=V0.as2, [644..647]=V1.as2, [648..651]=V0.ad2, [652..655]=V1.ad2,
// [656]=c.as2, [657]=c.ad2, [672..735]=ccomb = 2*cb2 + br1
__global__ __launch_bounds__(256) void prep1_kernel(
    const float* __restrict__ x, const float* __restrict__ W1,
    const float* __restrict__ as1, const float* __restrict__ ad1,
    const float* __restrict__ W2, const float* __restrict__ b1,
    const float* __restrict__ Wr1, const float* __restrict__ b2,
    const float* __restrict__ as2, const float* __restrict__ ad2,
    const float* __restrict__ br1,
    float* __restrict__ rec, float* __restrict__ al_d1, int* __restrict__ deg,
    int* __restrict__ bucket_cur, float* __restrict__ V, int N) {
    __shared__ float cs0[4], cs1[4], cd0[4], cd1[4];
    __shared__ float sV0[256], sV1[256], sc[64];
    int t = threadIdx.x;
    if (blockIdx.x == 0) bucket_cur[t] = t * BCAP;
    {
        float a = as1[t], d = ad1[t], u0 = W1[t], u1 = W1[256 + t];
        float p0 = wave_sum(u0 * a);
        float p1 = wave_sum(u1 * a);
        float q0 = wave_sum(u0 * d);
        float q1 = wave_sum(u1 * d);
        if ((t & 63) == 0) {
            int h = t >> 6;
            cs0[h] = p0; cs1[h] = p1; cd0[h] = q0; cd1[h] = q1;
        }
    }
    __syncthreads();
    int n = blockIdx.x * 256 + t;
    if (n < N) {
        deg[n] = 0;
        float2 xs = ((const float2*)x)[n];
        float4 vs, vd;
        vs.x = xs.x * cs0[0] + xs.y * cs1[0];
        vs.y = xs.x * cs0[1] + xs.y * cs1[1];
        vs.z = xs.x * cs0[2] + xs.y * cs1[2];
        vs.w = xs.x * cs0[3] + xs.y * cs1[3];
        vd.x = xs.x * cd0[0] + xs.y * cd1[0];
        vd.y = xs.x * cd0[1] + xs.y * cd1[1];
        vd.z = xs.x * cd0[2] + xs.y * cd1[2];
        vd.w = xs.x * cd0[3] + xs.y * cd1[3];
        ((float4*)rec)[2 * n] = vs;                         // al_s1[0..3]
        ((float4*)rec)[2 * n + 1] = make_float4(xs.x, xs.y, 0.f, 0.f);
        ((float4*)al_d1)[n] = vd;
    }
    // block 0 epilogue: fold W1@W2 (=V0,V1), b1@W2 (=c), then push Wr1/as2/ad2 through
    if (blockIdx.x == 0) {
        int h = t >> 6, j = t & 63;
        float v0 = 0.f, v1 = 0.f;
        for (int k = 0; k < 64; ++k) {
            float w2 = W2[(h * 64 + k) * 64 + j];
            v0 += W1[h * 64 + k] * w2;
            v1 += W1[256 + h * 64 + k] * w2;
        }
        sV0[t] = v0;
        sV1[t] = v1;
        if (t < 64) {
            float c = 0.f;
            for (int i = 0; i < 256; ++i) c += b1[i] * W2[i * 64 + t];
            sc[t] = c;
        }
        __syncthreads();
        float v0w = 0.f, v1w = 0.f;
        for (int k = 0; k < 64; ++k) {
            float wr = Wr1[k * 64 + j];
            v0w += sV0[h * 64 + k] * wr;
            v1w += sV1[h * 64 + k] * wr;
        }
        V[t] = v0w;
        V[256 + t] = v1w;
        if (t < 64) {
            float cw = 0.f, cb = 0.f;
            for (int k = 0; k < 64; ++k) {
                float wr = Wr1[k * 64 + t];
                cw += sc[k] * wr;
                cb += b2[k] * wr;
            }
            V[512 + t] = cw;
            V[576 + t] = cb;
            V[672 + t] = 2.f * cb + br1[t];   // ccomb for the edge regressor
        }
        int lane = t & 63;
        float p0 = wave_sum(sV0[t] * as2[lane]);
        float p1 = wave_sum(sV1[t] * as2[lane]);
        float q0 = wave_sum(sV0[t] * ad2[lane]);
        float q1 = wave_sum(sV1[t] * ad2[lane]);
        if (lane == 0) {
            V[640 + h] = p0; V[644 + h] = p1; V[648 + h] = q0; V[652 + h] = q1;
        }
        if (t < 64) {
            float r0 = wave_sum(sc[t] * as2[t]);
            float r1 = wave_sum(sc[t] * ad2[t]);
            if (t == 0) { V[656] = r0; V[657] = r1; }
        }
    }
}

// ---------------- Pass A: tile-sorted binning + fire-and-forget degree count ----------
// One block per 2048-edge tile. Rank edges per bucket with LDS atomics, block-scan the
// bucket counts, reserve global space with <=196 block-level atomics, reorder records
// bucket-contiguously in LDS, write out near-coalesced. ALSO bumps deg[dst] with a
// no-return global atomicAdd (throughput-fine; R8's disaster was fetch-add-with-return)
// so binB can skip its 19.2MB histogram pass.
// ebm.x = (src<<15) | ea15 ; ebm.y = (dst_local<<21) | eid
__global__ __launch_bounds__(256) void binA_kernel(
    const int* __restrict__ ei, const float* __restrict__ ea,
    int* __restrict__ bucket_cur, int* __restrict__ deg,
    uint2* __restrict__ ebm, int E, int nbuck) {
    __shared__ int cnt[NBUCK_MAX];
    __shared__ int gbase[NBUCK_MAX];
    __shared__ int lofs[NBUCK_MAX];
    __shared__ int psum[NBUCK_MAX];
    __shared__ uint2 buf[TILE];
    __shared__ unsigned short bkt[TILE];
    int t = threadIdx.x;
    int e0 = blockIdx.x * TILE;
    int cntE = min(TILE, E - e0);
    for (int i = t; i < nbuck; i += 256) cnt[i] = 0;
    __syncthreads();
    uint2 rec[8];
    int rb[8], rr[8];
#pragma unroll
    for (int i = 0; i < 8; ++i) {
        int e = e0 + i * 256 + t;
        if (i * 256 + t < cntE) {
            int s = ei[e], d = ei[E + e];
            unsigned q = (unsigned)(ea[e] * 32767.f + 0.5f);
            q = min(q, 32767u);
            rec[i] = make_uint2((((unsigned)s) << 15) | q,
                                (unsigned)(((d & 511) << 21) | e));
            rb[i] = d >> 9;
            rr[i] = atomicAdd(&cnt[rb[i]], 1);
            atomicAdd(&deg[d], 1);            // no-return degree count
        } else {
            rb[i] = -1;
        }
    }
    __syncthreads();
    // exclusive scan of cnt over [0, nbuck) + global reservation (one atomic/bucket)
    int v = (t < nbuck) ? cnt[t] : 0;
    psum[t] = v;
    __syncthreads();
    for (int o = 1; o < 256; o <<= 1) {
        int a = (t >= o) ? psum[t - o] : 0;
        __syncthreads();
        psum[t] += a;
        __syncthreads();
    }
    if (t < nbuck) {
        lofs[t] = psum[t] - v;
        if (v) gbase[t] = atomicAdd(&bucket_cur[t], v);
    }
    __syncthreads();
    // scatter into LDS, bucket-contiguous
#pragma unroll
    for (int i = 0; i < 8; ++i) {
        if (rb[i] >= 0) {
            int p = lofs[rb[i]] + rr[i];
            buf[p] = rec[i];
            bkt[p] = (unsigned short)rb[i];
        }
    }
    __syncthreads();
    // write out: consecutive p -> consecutive slots within each bucket's run
    for (int p = t; p < cntE; p += 256) {
        int b = bkt[p];
        ebm[gbase[b] + (p - lofs[b])] = buf[p];
    }
}

// ---------------- Pass B (slim): read deg, scan, scatter — histogram pass deleted -----
__global__ __launch_bounds__(256) void binB_kernel(
    const uint2* __restrict__ ebm, const int* __restrict__ bucket_cur,
    const int* __restrict__ deg, int* __restrict__ offs,
    unsigned* __restrict__ csr_se, int N) {
    __shared__ int lcur[512];
    __shared__ int psum[256];
    int b = blockIdx.x;
    int n0 = b << 9;
    int t = threadIdx.x;
    int na = n0 + 2 * t, nb2 = na + 1;
    int a0 = (na < N) ? deg[na] : 0;
    int a1 = (nb2 < N) ? deg[nb2] : 0;
    psum[t] = a0 + a1;
    __syncthreads();
    for (int o = 1; o < 256; o <<= 1) {
        int a = (t >= o) ? psum[t - o] : 0;
        __syncthreads();
        psum[t] += a;
        __syncthreads();
    }
    int excl = psum[t] - (a0 + a1);
    int bstart = b * BCAP;
    lcur[2 * t] = bstart + excl;
    lcur[2 * t + 1] = bstart + excl + a0;
    if (na < N) offs[na] = bstart + excl + a0;              // segment END
    if (nb2 < N) offs[nb2] = bstart + excl + a0 + a1;
    __syncthreads();
    int bend = bucket_cur[b];      // post-binA == region fill end
    for (int p = bstart + t; p < bend; p += 256) {
        uint2 m = ebm[p];
        int pos = atomicAdd(&lcur[m.y >> 21], 1);
        csr_se[pos] = m.x;
    }
}

// ---------------- Layer-1 aggregation: lane-per-edge-subset, all 4 heads per lane -----
// msg2y's proven decomposition: lane q of each quad walks edges j≡q (mod 4), computing
// ALL 4 heads (serial gather chain 4x shorter than lane-per-head; csr reads quad-
// coalesced; rec read as two full 16B loads). 12 accumulators butterfly-reduced over
// the quad; lane q writes head q's XA pair; lane 0 emits al_s2/al_d2.
__global__ __launch_bounds__(256) void aggX_kernel(
    const unsigned* __restrict__ csr_se, const int* __restrict__ offs,
    const int* __restrict__ deg,
    const float* __restrict__ rec, const float* __restrict__ al_d1,
    const float* __restrict__ We1, const float* __restrict__ ae1,
    const float* __restrict__ V,
    float2* __restrict__ XA, float* __restrict__ al_s2, float* __restrict__ al_d2,
    int N) {
    __shared__ float ce[4];
    __shared__ float sS[18];
    if (threadIdx.x < 18) sS[threadIdx.x] = V[640 + threadIdx.x];
    compute_ce1(We1, ae1, ce);
    int t = blockIdx.x * 256 + threadIdx.x;
    int n = t >> 2, q = t & 3;
    if (n >= N) return;
    int dc = deg[n];
    int start = offs[n] - dc;
    float4 ad = ((const float4*)al_d1)[n];
    float c0 = ce[0] * (1.f / 32767.f), c1 = ce[1] * (1.f / 32767.f);
    float c2 = ce[2] * (1.f / 32767.f), c3 = ce[3] * (1.f / 32767.f);
    const float4* r4 = (const float4*)rec;
    float z0 = 0.f, z1 = 0.f, z2 = 0.f, z3 = 0.f;
    float a0 = 0.f, a1 = 0.f, a2 = 0.f, a3 = 0.f;   // X0 per head
    float b0 = 0.f, b1 = 0.f, b2 = 0.f, b3 = 0.f;   // X1 per head
    int j = q;
    for (; j + 4 < dc; j += 8) {
        unsigned wA = csr_se[start + j];
        unsigned wB = csr_se[start + j + 4];
        int sA = wA >> 15, sB = wB >> 15;
        float qA = (float)(wA & 32767u), qB = (float)(wB & 32767u);
        float4 alsA = r4[(size_t)2 * sA];
        float4 xsA  = r4[(size_t)2 * sA + 1];
        float4 alsB = r4[(size_t)2 * sB];
        float4 xsB  = r4[(size_t)2 * sB + 1];
        float eA0 = __expf(lrelu(alsA.x + ad.x + qA * c0));
        float eA1 = __expf(lrelu(alsA.y + ad.y + qA * c1));
        float eA2 = __expf(lrelu(alsA.z + ad.z + qA * c2));
        float eA3 = __expf(lrelu(alsA.w + ad.w + qA * c3));
        float eB0 = __expf(lrelu(alsB.x + ad.x + qB * c0));
        float eB1 = __expf(lrelu(alsB.y + ad.y + qB * c1));
        float eB2 = __expf(lrelu(alsB.z + ad.z + qB * c2));
        float eB3 = __expf(lrelu(alsB.w + ad.w + qB * c3));
        z0 += eA0 + eB0; z1 += eA1 + eB1; z2 += eA2 + eB2; z3 += eA3 + eB3;
        a0 += eA0 * xsA.x + eB0 * xsB.x;
        a1 += eA1 * xsA.x + eB1 * xsB.x;
        a2 += eA2 * xsA.x + eB2 * xsB.x;
        a3 += eA3 * xsA.x + eB3 * xsB.x;
        b0 += eA0 * xsA.y + eB0 * xsB.y;
        b1 += eA1 * xsA.y + eB1 * xsB.y;
        b2 += eA2 * xsA.y + eB2 * xsB.y;
        b3 += eA3 * xsA.y + eB3 * xsB.y;
    }
    if (j < dc) {
        unsigned w = csr_se[start + j];
        int s = w >> 15;
        float qv = (float)(w & 32767u);
        float4 als = r4[(size_t)2 * s];
        float4 xs  = r4[(size_t)2 * s + 1];
        float e0 = __expf(lrelu(als.x + ad.x + qv * c0));
        float e1 = __expf(lrelu(als.y + ad.y + qv * c1));
        float e2 = __expf(lrelu(als.z + ad.z + qv * c2));
        float e3 = __expf(lrelu(als.w + ad.w + qv * c3));
        z0 += e0; z1 += e1; z2 += e2; z3 += e3;
        a0 += e0 * xs.x; a1 += e1 * xs.x; a2 += e2 * xs.x; a3 += e3 * xs.x;
        b0 += e0 * xs.y; b1 += e1 * xs.y; b2 += e2 * xs.y; b3 += e3 * xs.y;
    }
    // butterfly-reduce 12 accumulators over the quad
    z0 += __shfl_xor(z0, 1, 64); z0 += __shfl_xor(z0, 2, 64);
    z1 += __shfl_xor(z1, 1, 64); z1 += __shfl_xor(z1, 2, 64);
    z2 += __shfl_xor(z2, 1, 64); z2 += __shfl_xor(z2, 2, 64);
    z3 += __shfl_xor(z3, 1, 64); z3 += __shfl_xor(z3, 2, 64);
    a0 += __shfl_xor(a0, 1, 64); a0 += __shfl_xor(a0, 2, 64);
    a1 += __shfl_xor(a1, 1, 64); a1 += __shfl_xor(a1, 2, 64);
    a2 += __shfl_xor(a2, 1, 64); a2 += __shfl_xor(a2, 2, 64);
    a3 += __shfl_xor(a3, 1, 64); a3 += __shfl_xor(a3, 2, 64);
    b0 += __shfl_xor(b0, 1, 64); b0 += __shfl_xor(b0, 2, 64);
    b1 += __shfl_xor(b1, 1, 64); b1 += __shfl_xor(b1, 2, 64);
    b2 += __shfl_xor(b2, 1, 64); b2 += __shfl_xor(b2, 2, 64);
    b3 += __shfl_xor(b3, 1, 64); b3 += __shfl_xor(b3, 2, 64);
    float i0 = 1.f / (z0 + 1e-16f);
    float i1 = 1.f / (z1 + 1e-16f);
    float i2 = 1.f / (z2 + 1e-16f);
    float i3 = 1.f / (z3 + 1e-16f);
    float xa0h = (q == 0) ? a0 * i0 : (q == 1) ? a1 * i1 : (q == 2) ? a2 * i2 : a3 * i3;
    float xa1h = (q == 0) ? b0 * i0 : (q == 1) ? b1 * i1 : (q == 2) ? b2 * i2 : b3 * i3;
    XA[(size_t)4 * n + q] = make_float2(xa0h, xa1h);
    if (q == 0) {
        float x00 = a0 * i0, x01 = a1 * i1, x02 = a2 * i2, x03 = a3 * i3;
        float x10 = b0 * i0, x11 = b1 * i1, x12 = b2 * i2, x13 = b3 * i3;
        float ps = x00 * sS[0] + x01 * sS[1] + x02 * sS[2] + x03 * sS[3]
                 + x10 * sS[4] + x11 * sS[5] + x12 * sS[6] + x13 * sS[7];
        float pd = x00 * sS[8] + x01 * sS[9] + x02 * sS[10] + x03 * sS[11]
                 + x10 * sS[12] + x11 * sS[13] + x12 * sS[14] + x13 * sS[15];
        al_s2[n] = sS[16] + ps;
        al_d2[n] = sS[17] + pd;
    }
}

// ---------------- Layer-2 rank-8 aggregation -> packed fp16 (Y[8]) + w0 per node -----
// One lane per edge; 32B XA gathers (L2-resident 3.2MB table); exp once per edge.
// al_s2[src] is recomputed IN-REGISTER from the gathered XA fragments (8 FMA) instead
// of a dependent 4B gather — one fewer random load stream per edge.
__global__ __launch_bounds__(256) void msg2y_kernel(
    const unsigned* __restrict__ csr_se, const int* __restrict__ offs,
    const int* __restrict__ deg,
    const float* __restrict__ al_d2,
    const float* __restrict__ We2, const float* __restrict__ ae2,
    const float* __restrict__ V,
    const float2* __restrict__ XA,
    uint4* __restrict__ Yh, float* __restrict__ w0n, int N) {
    __shared__ float sh[1];
    float ce2 = compute_ce2(We2, ae2, sh) * (1.f / 32767.f);
    float s16 = V[656];
    float ss0 = V[640], ss1 = V[641], ss2 = V[642], ss3 = V[643];
    float ss4 = V[644], ss5 = V[645], ss6 = V[646], ss7 = V[647];
    int t = blockIdx.x * 256 + threadIdx.x;
    int n = t >> 2, q = t & 3;
    if (n >= N) return;
    int dc = deg[n];
    int start = offs[n] - dc;
    float ald = al_d2[n];
    const float4* xa4 = (const float4*)XA;   // node s -> xa4[2s], xa4[2s+1]
    float y0 = 0.f, y1 = 0.f, y2 = 0.f, y3 = 0.f;
    float y4 = 0.f, y5 = 0.f, y6 = 0.f, y7 = 0.f;
    float z = 0.f;
    int j = q;
    for (; j + 4 < dc; j += 8) {
        unsigned wA = csr_se[start + j];
        unsigned wB = csr_se[start + j + 4];
        int sA = wA >> 15, sB = wB >> 15;
        float4 a0 = xa4[(size_t)sA * 2];
        float4 a1 = xa4[(size_t)sA * 2 + 1];
        float4 b0 = xa4[(size_t)sB * 2];
        float4 b1 = xa4[(size_t)sB * 2 + 1];
        float alsA = s16 + a0.x * ss0 + a0.y * ss4 + a0.z * ss1 + a0.w * ss5
                         + a1.x * ss2 + a1.y * ss6 + a1.z * ss3 + a1.w * ss7;
        float alsB = s16 + b0.x * ss0 + b0.y * ss4 + b0.z * ss1 + b0.w * ss5
                         + b1.x * ss2 + b1.y * ss6 + b1.z * ss3 + b1.w * ss7;
        float exA = __expf(lrelu(alsA + ald + (float)(wA & 32767u) * ce2));
        float exB = __expf(lrelu(alsB + ald + (float)(wB & 32767u) * ce2));
        z += exA + exB;
        y0 += exA * a0.x + exB * b0.x;
        y1 += exA * a0.y + exB * b0.y;
        y2 += exA * a0.z + exB * b0.z;
        y3 += exA * a0.w + exB * b0.w;
        y4 += exA * a1.x + exB * b1.x;
        y5 += exA * a1.y + exB * b1.y;
        y6 += exA * a1.z + exB * b1.z;
        y7 += exA * a1.w + exB * b1.w;
    }
    if (j < dc) {
        unsigned w = csr_se[start + j];
        int s = w >> 15;
        float4 a0 = xa4[(size_t)s * 2];
        float4 a1 = xa4[(size_t)s * 2 + 1];
        float als = s16 + a0.x * ss0 + a0.y * ss4 + a0.z * ss1 + a0.w * ss5
                        + a1.x * ss2 + a1.y * ss6 + a1.z * ss3 + a1.w * ss7;
        float ex = __expf(lrelu(als + ald + (float)(w & 32767u) * ce2));
        z += ex;
        y0 += ex * a0.x; y1 += ex * a0.y; y2 += ex * a0.z; y3 += ex * a0.w;
        y4 += ex * a1.x; y5 += ex * a1.y; y6 += ex * a1.z; y7 += ex * a1.w;
    }
    // reduce 9 accumulators across the 4-lane group (xor butterfly -> all lanes full)
    y0 += __shfl_xor(y0, 1, 64); y0 += __shfl_xor(y0, 2, 64);
    y1 += __shfl_xor(y1, 1, 64); y1 += __shfl_xor(y1, 2, 64);
    y2 += __shfl_xor(y2, 1, 64); y2 += __shfl_xor(y2, 2, 64);
    y3 += __shfl_xor(y3, 1, 64); y3 += __shfl_xor(y3, 2, 64);
    y4 += __shfl_xor(y4, 1, 64); y4 += __shfl_xor(y4, 2, 64);
    y5 += __shfl_xor(y5, 1, 64); y5 += __shfl_xor(y5, 2, 64);
    y6 += __shfl_xor(y6, 1, 64); y6 += __shfl_xor(y6, 2, 64);
    y7 += __shfl_xor(y7, 1, 64); y7 += __shfl_xor(y7, 2, 64);
    z += __shfl_xor(z, 1, 64); z += __shfl_xor(z, 2, 64);
    if (q == 0) {
        float inv = 1.f / (z + 1e-16f);
        __half2 p0 = __floats2half2_rn(y0 * inv, y1 * inv);
        __half2 p1 = __floats2half2_rn(y2 * inv, y3 * inv);
        __half2 p2 = __floats2half2_rn(y4 * inv, y5 * inv);
        __half2 p3 = __floats2half2_rn(y6 * inv, y7 * inv);
        uint4 o;
        o.x = *(unsigned*)&p0; o.y = *(unsigned*)&p1;
        o.z = *(unsigned*)&p2; o.w = *(unsigned*)&p3;
        Yh[n] = o;
        w0n[n] = z * inv;   // ~1, or 0 for empty segments (kills cW term)
    }
}

// ---------------- Edge regressor: thread/edge, scalar basis, PACKED fp32 math ---------
// k-loop over dim PAIRS with ext_vector float2 ops -> v_pk_fma_f32 (2 FMA/instr).
// Basis pairs are wave-uniform 8B loads (s_load_dwordx2). ccomb in V[672..735].
__global__ __launch_bounds__(256) void edge_kernel(
    const int* __restrict__ ei,
    const uint4* __restrict__ Yh, const float* __restrict__ w0n,
    const float* __restrict__ V,
    const float* __restrict__ Wr2,
    const float* __restrict__ br2, float* __restrict__ out, int E) {
    int e = blockIdx.x * 256 + threadIdx.x;
    if (e >= E) return;
    int s = ei[e], d = ei[E + e];
    uint4 ys = Yh[s], yd = Yh[d];
    float w0 = w0n[s] + w0n[d];
    float fs[8], fd[8], tt[8];
    h8_to_f(ys, fs);
    h8_to_f(yd, fd);
#pragma unroll
    for (int i = 0; i < 8; ++i) tt[i] = fs[i] + fd[i];
    v2f acc = {0.f, 0.f};
    v2f w0v = {w0, w0};
#pragma unroll
    for (int k = 0; k < 64; k += 2) {
        v2f g = w0v * (*(const v2f*)(V + 512 + k));
        g += *(const v2f*)(V + 672 + k);
        g += (v2f){tt[0], tt[0]} * (*(const v2f*)(V + k));
        g += (v2f){tt[1], tt[1]} * (*(const v2f*)(V + 256 + k));
        g += (v2f){tt[2], tt[2]} * (*(const v2f*)(V + 64 + k));
        g += (v2f){tt[3], tt[3]} * (*(const v2f*)(V + 320 + k));
        g += (v2f){tt[4], tt[4]} * (*(const v2f*)(V + 128 + k));
        g += (v2f){tt[5], tt[5]} * (*(const v2f*)(V + 384 + k));
        g += (v2f){tt[6], tt[6]} * (*(const v2f*)(V + 192 + k));
        g += (v2f){tt[7], tt[7]} * (*(const v2f*)(V + 448 + k));
        g = __builtin_elementwise_max(g, (v2f){0.f, 0.f});
        acc += g * (*(const v2f*)(Wr2 + k));
    }
    out[e] = acc.x + acc.y + br2[0];
}

extern "C" void kernel_launch(void* const* d_in, const int* in_sizes, int n_in,
                              void* d_out, int out_size, void* d_ws, size_t ws_size,
                              hipStream_t stream) {
    const float* x    = (const float*)d_in[0];
    const int*   ei   = (const int*)d_in[1];
    const float* ea   = (const float*)d_in[2];
    const float* W1   = (const float*)d_in[3];
    const float* We1  = (const float*)d_in[4];
    const float* as1  = (const float*)d_in[5];
    const float* ad1  = (const float*)d_in[6];
    const float* ae1  = (const float*)d_in[7];
    const float* b1   = (const float*)d_in[8];
    const float* W2   = (const float*)d_in[9];
    const float* We2  = (const float*)d_in[10];
    const float* as2  = (const float*)d_in[11];
    const float* ad2  = (const float*)d_in[12];
    const float* ae2  = (const float*)d_in[13];
    const float* b2   = (const float*)d_in[14];
    const float* Wr1  = (const float*)d_in[15];
    const float* br1  = (const float*)d_in[16];
    const float* Wr2  = (const float*)d_in[17];
    const float* br2  = (const float*)d_in[18];
    float* out = (float*)d_out;

    const int N = in_sizes[0] / 2;
    const int E = in_sizes[2];
    const int nbuck = (N + 511) >> 9;
    const size_t capE = (size_t)nbuck * BCAP;   // fixed-capacity CSR address space

    // workspace layout
    float* ws = (float*)d_ws;
    float*    rec   = ws;                            // N*8 {al_s1[4], x0, x1, pad, pad}
    float*    al_d1 = rec + (size_t)N * 8;           // N*4
    float*    al_s2 = al_d1 + (size_t)N * 4;         // N
    float*    al_d2 = al_s2 + N;                     // N
    float2*   XA    = (float2*)((((uintptr_t)(al_d2 + N)) + 31) & ~(uintptr_t)31); // N*4 float2 (32B aligned)
    float*    V     = (float*)((((uintptr_t)(XA + (size_t)N * 4)) + 15) & ~(uintptr_t)15); // 736 (pad 768)
    int*      deg   = (int*)(V + 768);               // N
    int*      offs  = deg + N;                       // N
    int*      bucket_cur  = offs + N;                // 256
    uint4*    Yh    = (uint4*)((((uintptr_t)(bucket_cur + 256)) + 15) & ~(uintptr_t)15); // N uint4
    float*    w0n   = (float*)(Yh + N);              // N
    uint2*    ebm   = (uint2*)((((uintptr_t)(w0n + N)) + 15) & ~(uintptr_t)15); // capE uint2
    unsigned* csr_se = (unsigned*)(ebm + capE);      // capE

    const int nb = (N + 255) / 256;

    prep1_kernel<<<nb, 256, 0, stream>>>(x, W1, as1, ad1, W2, b1, Wr1, b2, as2, ad2,
                                         br1, rec, al_d1, deg, bucket_cur, V, N);
    binA_kernel<<<(E + TILE - 1) / TILE, 256, 0, stream>>>(ei, ea, bucket_cur, deg,
                                                           ebm, E, nbuck);
    binB_kernel<<<nbuck, 256, 0, stream>>>(ebm, bucket_cur, deg, offs, csr_se, N);
    aggX_kernel<<<(4 * N + 255) / 256, 256, 0, stream>>>(csr_se, offs, deg,
                                                         rec, al_d1, We1, ae1, V,
                                                         XA, al_s2, al_d2, N);
    msg2y_kernel<<<(4 * N + 255) / 256, 256, 0, stream>>>(csr_se, offs, deg,
                                                          al_d2, We2, ae2, V, XA,
                                                          Yh, w0n, N);
    edge_kernel<<<(E + 255) / 256, 256, 0, stream>>>(ei, Yh, w0n, V, Wr2, br2,
                                                     out, E);
}

// Round 14
// 222.234 us; speedup vs baseline: 1.2507x; 1.2507x over previous
//
#include <hip/hip_runtime.h>
#include <hip/hip_bf16.h>
#include <hip/hip_fp16.h>

#define NEG_SLOPE 0.2f
#define NBUCK_MAX 256   // buckets of 512 nodes; 100k nodes -> 196 buckets
#define BCAP 12288      // fixed bucket capacity (mean 8163, sigma ~90 -> 45 sigma slack)
#define TILE 2048       // edges per binA block (8 per thread)

typedef float v2f __attribute__((ext_vector_type(2)));

__device__ __forceinline__ float lrelu(float v) { return v >= 0.f ? v : NEG_SLOPE * v; }

__device__ __forceinline__ float wave_sum(float v) {
    for (int o = 32; o; o >>= 1) v += __shfl_down(v, o, 64);
    return v;
}

__device__ __forceinline__ void h8_to_f(const uint4 v, float* f) {
    float2 a = __half22float2(*(const __half2*)&v.x);
    float2 b = __half22float2(*(const __half2*)&v.y);
    float2 c = __half22float2(*(const __half2*)&v.z);
    float2 d = __half22float2(*(const __half2*)&v.w);
    f[0] = a.x; f[1] = a.y; f[2] = b.x; f[3] = b.y;
    f[4] = c.x; f[5] = c.y; f[6] = d.x; f[7] = d.y;
}

// ce1[h] = dot(We1[h*64..], ae1[h*64..]) — wave h computes head h. 256 threads.
__device__ __forceinline__ void compute_ce1(const float* __restrict__ We1,
                                            const float* __restrict__ ae1,
                                            float* ce /*shared[4]*/) {
    int t = threadIdx.x;
    float p = wave_sum(We1[t] * ae1[t]);
    if ((t & 63) == 0) ce[t >> 6] = p;
    __syncthreads();
}

__device__ __forceinline__ float compute_ce2(const float* __restrict__ We2,
                                             const float* __restrict__ ae2,
                                             float* sh /*shared[1]*/) {
    int t = threadIdx.x;
    if (t < 64) {
        float p = wave_sum(We2[t] * ae2[t]);
        if (t == 0) sh[0] = p;
    }
    __syncthreads();
    return sh[0];
}

// ---------------- Layer-1 prep: node rec {al_s1[4],x0,x1}; al_d1; folded V -----------
// V layout (global): [0..255]=V0W, [256..511]=V1W, [512..575]=cW, [576..639]=cb2,
// [640..643]=V0.as2, [644..647]=V1.as2, [648..651]=V0.ad2, [652..655]=V1.ad2,
// [656]=c.as2, [657]=c.ad2, [672..735]=ccomb = 2*cb2 + br1
__global__ __launch_bounds__(256) void prep1_kernel(
    const float* __restrict__ x, const float* __restrict__ W1,
    const float* __restrict__ as1, const float* __restrict__ ad1,
    const float* __restrict__ W2, const float* __restrict__ b1,
    const float* __restrict__ Wr1, const float* __restrict__ b2,
    const float* __restrict__ as2, const float* __restrict__ ad2,
    const float* __restrict__ br1,
    float* __restrict__ rec, float* __restrict__ al_d1,
    int* __restrict__ bucket_cur, float* __restrict__ V, int N) {
    __shared__ float cs0[4], cs1[4], cd0[4], cd1[4];
    __shared__ float sV0[256], sV1[256], sc[64];
    int t = threadIdx.x;
    if (blockIdx.x == 0) bucket_cur[t] = t * BCAP;
    {
        float a = as1[t], d = ad1[t], u0 = W1[t], u1 = W1[256 + t];
        float p0 = wave_sum(u0 * a);
        float p1 = wave_sum(u1 * a);
        float q0 = wave_sum(u0 * d);
        float q1 = wave_sum(u1 * d);
        if ((t & 63) == 0) {
            int h = t >> 6;
            cs0[h] = p0; cs1[h] = p1; cd0[h] = q0; cd1[h] = q1;
        }
    }
    __syncthreads();
    int n = blockIdx.x * 256 + t;
    if (n < N) {
        float2 xs = ((const float2*)x)[n];
        float4 vs, vd;
        vs.x = xs.x * cs0[0] + xs.y * cs1[0];
        vs.y = xs.x * cs0[1] + xs.y * cs1[1];
        vs.z = xs.x * cs0[2] + xs.y * cs1[2];
        vs.w = xs.x * cs0[3] + xs.y * cs1[3];
        vd.x = xs.x * cd0[0] + xs.y * cd1[0];
        vd.y = xs.x * cd0[1] + xs.y * cd1[1];
        vd.z = xs.x * cd0[2] + xs.y * cd1[2];
        vd.w = xs.x * cd0[3] + xs.y * cd1[3];
        ((float4*)rec)[2 * n] = vs;                         // al_s1[0..3]
        ((float4*)rec)[2 * n + 1] = make_float4(xs.x, xs.y, 0.f, 0.f);
        ((float4*)al_d1)[n] = vd;
    }
    // block 0 epilogue: fold W1@W2 (=V0,V1), b1@W2 (=c), then push Wr1/as2/ad2 through
    if (blockIdx.x == 0) {
        int h = t >> 6, j = t & 63;
        float v0 = 0.f, v1 = 0.f;
        for (int k = 0; k < 64; ++k) {
            float w2 = W2[(h * 64 + k) * 64 + j];
            v0 += W1[h * 64 + k] * w2;
            v1 += W1[256 + h * 64 + k] * w2;
        }
        sV0[t] = v0;
        sV1[t] = v1;
        if (t < 64) {
            float c = 0.f;
            for (int i = 0; i < 256; ++i) c += b1[i] * W2[i * 64 + t];
            sc[t] = c;
        }
        __syncthreads();
        float v0w = 0.f, v1w = 0.f;
        for (int k = 0; k < 64; ++k) {
            float wr = Wr1[k * 64 + j];
            v0w += sV0[h * 64 + k] * wr;
            v1w += sV1[h * 64 + k] * wr;
        }
        V[t] = v0w;
        V[256 + t] = v1w;
        if (t < 64) {
            float cw = 0.f, cb = 0.f;
            for (int k = 0; k < 64; ++k) {
                float wr = Wr1[k * 64 + t];
                cw += sc[k] * wr;
                cb += b2[k] * wr;
            }
            V[512 + t] = cw;
            V[576 + t] = cb;
            V[672 + t] = 2.f * cb + br1[t];   // ccomb for the edge regressor
        }
        int lane = t & 63;
        float p0 = wave_sum(sV0[t] * as2[lane]);
        float p1 = wave_sum(sV1[t] * as2[lane]);
        float q0 = wave_sum(sV0[t] * ad2[lane]);
        float q1 = wave_sum(sV1[t] * ad2[lane]);
        if (lane == 0) {
            V[640 + h] = p0; V[644 + h] = p1; V[648 + h] = q0; V[652 + h] = q1;
        }
        if (t < 64) {
            float r0 = wave_sum(sc[t] * as2[t]);
            float r1 = wave_sum(sc[t] * ad2[t]);
            if (t == 0) { V[656] = r0; V[657] = r1; }
        }
    }
}

// ---------------- Pass A: tile-sorted binning (single pass over edges) ----------------
// One block per 2048-edge tile. Rank edges per bucket with LDS atomics, block-scan the
// bucket counts, reserve global space with <=196 block-level atomics (never per-edge),
// reorder records bucket-contiguously in LDS, then write out in position order.
// NO per-edge global atomics of any kind (R13 lesson: even no-return deg atomics cost
// +57 µs via cross-XCD dirty-line migration).
// ebm.x = (src<<15) | ea15 ; ebm.y = (dst_local<<21) | eid
__global__ __launch_bounds__(256) void binA_kernel(
    const int* __restrict__ ei, const float* __restrict__ ea,
    int* __restrict__ bucket_cur, uint2* __restrict__ ebm, int E, int nbuck) {
    __shared__ int cnt[NBUCK_MAX];
    __shared__ int gbase[NBUCK_MAX];
    __shared__ int lofs[NBUCK_MAX];
    __shared__ int psum[NBUCK_MAX];
    __shared__ uint2 buf[TILE];
    __shared__ unsigned short bkt[TILE];
    int t = threadIdx.x;
    int e0 = blockIdx.x * TILE;
    int cntE = min(TILE, E - e0);
    for (int i = t; i < nbuck; i += 256) cnt[i] = 0;
    __syncthreads();
    uint2 rec[8];
    int rb[8], rr[8];
#pragma unroll
    for (int i = 0; i < 8; ++i) {
        int e = e0 + i * 256 + t;
        if (i * 256 + t < cntE) {
            int s = ei[e], d = ei[E + e];
            unsigned q = (unsigned)(ea[e] * 32767.f + 0.5f);
            q = min(q, 32767u);
            rec[i] = make_uint2((((unsigned)s) << 15) | q,
                                (unsigned)(((d & 511) << 21) | e));
            rb[i] = d >> 9;
            rr[i] = atomicAdd(&cnt[rb[i]], 1);
        } else {
            rb[i] = -1;
        }
    }
    __syncthreads();
    // exclusive scan of cnt over [0, nbuck) + global reservation (one atomic/bucket)
    int v = (t < nbuck) ? cnt[t] : 0;
    psum[t] = v;
    __syncthreads();
    for (int o = 1; o < 256; o <<= 1) {
        int a = (t >= o) ? psum[t - o] : 0;
        __syncthreads();
        psum[t] += a;
        __syncthreads();
    }
    if (t < nbuck) {
        lofs[t] = psum[t] - v;
        if (v) gbase[t] = atomicAdd(&bucket_cur[t], v);
    }
    __syncthreads();
    // scatter into LDS, bucket-contiguous
#pragma unroll
    for (int i = 0; i < 8; ++i) {
        if (rb[i] >= 0) {
            int p = lofs[rb[i]] + rr[i];
            buf[p] = rec[i];
            bkt[p] = (unsigned short)rb[i];
        }
    }
    __syncthreads();
    // write out: consecutive p -> consecutive slots within each bucket's run
    for (int p = t; p < cntE; p += 256) {
        int b = bkt[p];
        ebm[gbase[b] + (p - lofs[b])] = buf[p];
    }
}

// ---------------- Pass B: per bucket — LDS deg-histogram, local scan, exact scatter ----
__global__ __launch_bounds__(256) void binB_kernel(
    const uint2* __restrict__ ebm, const int* __restrict__ bucket_cur,
    int* __restrict__ deg, int* __restrict__ offs,
    unsigned* __restrict__ csr_se, int N) {
    __shared__ int lcnt[512];
    __shared__ int lofs[512];
    __shared__ int lcur[512];
    int b = blockIdx.x;
    int n0 = b << 9;
    int t = threadIdx.x;
    lcnt[t] = 0; lcnt[t + 256] = 0;
    __syncthreads();
    int bstart = b * BCAP;
    int bend = bucket_cur[b];      // post-binA == region fill end
    for (int p = bstart + t; p < bend; p += 256)
        atomicAdd(&lcnt[ebm[p].y >> 21], 1);
    __syncthreads();
    int a0 = lcnt[2 * t], a1 = lcnt[2 * t + 1];
    __shared__ int psum[256];
    psum[t] = a0 + a1;
    __syncthreads();
    for (int o = 1; o < 256; o <<= 1) {
        int a = (t >= o) ? psum[t - o] : 0;
        __syncthreads();
        psum[t] += a;
        __syncthreads();
    }
    int excl = psum[t] - (a0 + a1);
    lofs[2 * t] = excl;
    lofs[2 * t + 1] = excl + a0;
    lcur[2 * t] = bstart + excl;
    lcur[2 * t + 1] = bstart + excl + a0;
    __syncthreads();
    for (int i = t; i < 512; i += 256) {
        int n = n0 + i;
        if (n < N) {
            deg[n] = lcnt[i];
            offs[n] = bstart + lofs[i] + lcnt[i];   // segment END (fixed address space)
        }
    }
    for (int p = bstart + t; p < bend; p += 256) {
        uint2 m = ebm[p];
        int pos = atomicAdd(&lcur[m.y >> 21], 1);
        csr_se[pos] = m.x;
    }
}

// ---------------- Layer-1 aggregation: lane-per-edge-subset, all 4 heads per lane -----
// msg2y's proven decomposition: lane q of each quad walks edges j≡q (mod 4), computing
// ALL 4 heads (serial gather chain 4x shorter than lane-per-head; csr reads quad-
// coalesced; rec read as two full 16B loads). 12 accumulators butterfly-reduced over
// the quad; lane q writes head q's XA pair; lane 0 emits al_s2/al_d2.
__global__ __launch_bounds__(256) void aggX_kernel(
    const unsigned* __restrict__ csr_se, const int* __restrict__ offs,
    const int* __restrict__ deg,
    const float* __restrict__ rec, const float* __restrict__ al_d1,
    const float* __restrict__ We1, const float* __restrict__ ae1,
    const float* __restrict__ V,
    float2* __restrict__ XA, float* __restrict__ al_s2, float* __restrict__ al_d2,
    int N) {
    __shared__ float ce[4];
    __shared__ float sS[18];
    if (threadIdx.x < 18) sS[threadIdx.x] = V[640 + threadIdx.x];
    compute_ce1(We1, ae1, ce);
    int t = blockIdx.x * 256 + threadIdx.x;
    int n = t >> 2, q = t & 3;
    if (n >= N) return;
    int dc = deg[n];
    int start = offs[n] - dc;
    float4 ad = ((const float4*)al_d1)[n];
    float c0 = ce[0] * (1.f / 32767.f), c1 = ce[1] * (1.f / 32767.f);
    float c2 = ce[2] * (1.f / 32767.f), c3 = ce[3] * (1.f / 32767.f);
    const float4* r4 = (const float4*)rec;
    float z0 = 0.f, z1 = 0.f, z2 = 0.f, z3 = 0.f;
    float a0 = 0.f, a1 = 0.f, a2 = 0.f, a3 = 0.f;   // X0 per head
    float b0 = 0.f, b1 = 0.f, b2 = 0.f, b3 = 0.f;   // X1 per head
    int j = q;
    for (; j + 4 < dc; j += 8) {
        unsigned wA = csr_se[start + j];
        unsigned wB = csr_se[start + j + 4];
        int sA = wA >> 15, sB = wB >> 15;
        float qA = (float)(wA & 32767u), qB = (float)(wB & 32767u);
        float4 alsA = r4[(size_t)2 * sA];
        float4 xsA  = r4[(size_t)2 * sA + 1];
        float4 alsB = r4[(size_t)2 * sB];
        float4 xsB  = r4[(size_t)2 * sB + 1];
        float eA0 = __expf(lrelu(alsA.x + ad.x + qA * c0));
        float eA1 = __expf(lrelu(alsA.y + ad.y + qA * c1));
        float eA2 = __expf(lrelu(alsA.z + ad.z + qA * c2));
        float eA3 = __expf(lrelu(alsA.w + ad.w + qA * c3));
        float eB0 = __expf(lrelu(alsB.x + ad.x + qB * c0));
        float eB1 = __expf(lrelu(alsB.y + ad.y + qB * c1));
        float eB2 = __expf(lrelu(alsB.z + ad.z + qB * c2));
        float eB3 = __expf(lrelu(alsB.w + ad.w + qB * c3));
        z0 += eA0 + eB0; z1 += eA1 + eB1; z2 += eA2 + eB2; z3 += eA3 + eB3;
        a0 += eA0 * xsA.x + eB0 * xsB.x;
        a1 += eA1 * xsA.x + eB1 * xsB.x;
        a2 += eA2 * xsA.x + eB2 * xsB.x;
        a3 += eA3 * xsA.x + eB3 * xsB.x;
        b0 += eA0 * xsA.y + eB0 * xsB.y;
        b1 += eA1 * xsA.y + eB1 * xsB.y;
        b2 += eA2 * xsA.y + eB2 * xsB.y;
        b3 += eA3 * xsA.y + eB3 * xsB.y;
    }
    if (j < dc) {
        unsigned w = csr_se[start + j];
        int s = w >> 15;
        float qv = (float)(w & 32767u);
        float4 als = r4[(size_t)2 * s];
        float4 xs  = r4[(size_t)2 * s + 1];
        float e0 = __expf(lrelu(als.x + ad.x + qv * c0));
        float e1 = __expf(lrelu(als.y + ad.y + qv * c1));
        float e2 = __expf(lrelu(als.z + ad.z + qv * c2));
        float e3 = __expf(lrelu(als.w + ad.w + qv * c3));
        z0 += e0; z1 += e1; z2 += e2; z3 += e3;
        a0 += e0 * xs.x; a1 += e1 * xs.x; a2 += e2 * xs.x; a3 += e3 * xs.x;
        b0 += e0 * xs.y; b1 += e1 * xs.y; b2 += e2 * xs.y; b3 += e3 * xs.y;
    }
    // butterfly-reduce 12 accumulators over the quad
    z0 += __shfl_xor(z0, 1, 64); z0 += __shfl_xor(z0, 2, 64);
    z1 += __shfl_xor(z1, 1, 64); z1 += __shfl_xor(z1, 2, 64);
    z2 += __shfl_xor(z2, 1, 64); z2 += __shfl_xor(z2, 2, 64);
    z3 += __shfl_xor(z3, 1, 64); z3 += __shfl_xor(z3, 2, 64);
    a0 += __shfl_xor(a0, 1, 64); a0 += __shfl_xor(a0, 2, 64);
    a1 += __shfl_xor(a1, 1, 64); a1 += __shfl_xor(a1, 2, 64);
    a2 += __shfl_xor(a2, 1, 64); a2 += __shfl_xor(a2, 2, 64);
    a3 += __shfl_xor(a3, 1, 64); a3 += __shfl_xor(a3, 2, 64);
    b0 += __shfl_xor(b0, 1, 64); b0 += __shfl_xor(b0, 2, 64);
    b1 += __shfl_xor(b1, 1, 64); b1 += __shfl_xor(b1, 2, 64);
    b2 += __shfl_xor(b2, 1, 64); b2 += __shfl_xor(b2, 2, 64);
    b3 += __shfl_xor(b3, 1, 64); b3 += __shfl_xor(b3, 2, 64);
    float i0 = 1.f / (z0 + 1e-16f);
    float i1 = 1.f / (z1 + 1e-16f);
    float i2 = 1.f / (z2 + 1e-16f);
    float i3 = 1.f / (z3 + 1e-16f);
    float xa0h = (q == 0) ? a0 * i0 : (q == 1) ? a1 * i1 : (q == 2) ? a2 * i2 : a3 * i3;
    float xa1h = (q == 0) ? b0 * i0 : (q == 1) ? b1 * i1 : (q == 2) ? b2 * i2 : b3 * i3;
    XA[(size_t)4 * n + q] = make_float2(xa0h, xa1h);
    if (q == 0) {
        float x00 = a0 * i0, x01 = a1 * i1, x02 = a2 * i2, x03 = a3 * i3;
        float x10 = b0 * i0, x11 = b1 * i1, x12 = b2 * i2, x13 = b3 * i3;
        float ps = x00 * sS[0] + x01 * sS[1] + x02 * sS[2] + x03 * sS[3]
                 + x10 * sS[4] + x11 * sS[5] + x12 * sS[6] + x13 * sS[7];
        float pd = x00 * sS[8] + x01 * sS[9] + x02 * sS[10] + x03 * sS[11]
                 + x10 * sS[12] + x11 * sS[13] + x12 * sS[14] + x13 * sS[15];
        al_s2[n] = sS[16] + ps;
        al_d2[n] = sS[17] + pd;
    }
}

// ---------------- Layer-2 rank-8 aggregation -> packed fp16 (Y[8]) + w0 per node -----
// One lane per edge; 32B XA gathers (L2-resident 3.2MB table); exp once per edge.
// al_s2[src] is recomputed IN-REGISTER from the gathered XA fragments (8 FMA) instead
// of a dependent 4B gather — one fewer random load stream per edge.
__global__ __launch_bounds__(256) void msg2y_kernel(
    const unsigned* __restrict__ csr_se, const int* __restrict__ offs,
    const int* __restrict__ deg,
    const float* __restrict__ al_d2,
    const float* __restrict__ We2, const float* __restrict__ ae2,
    const float* __restrict__ V,
    const float2* __restrict__ XA,
    uint4* __restrict__ Yh, float* __restrict__ w0n, int N) {
    __shared__ float sh[1];
    float ce2 = compute_ce2(We2, ae2, sh) * (1.f / 32767.f);
    float s16 = V[656];
    float ss0 = V[640], ss1 = V[641], ss2 = V[642], ss3 = V[643];
    float ss4 = V[644], ss5 = V[645], ss6 = V[646], ss7 = V[647];
    int t = blockIdx.x * 256 + threadIdx.x;
    int n = t >> 2, q = t & 3;
    if (n >= N) return;
    int dc = deg[n];
    int start = offs[n] - dc;
    float ald = al_d2[n];
    const float4* xa4 = (const float4*)XA;   // node s -> xa4[2s], xa4[2s+1]
    float y0 = 0.f, y1 = 0.f, y2 = 0.f, y3 = 0.f;
    float y4 = 0.f, y5 = 0.f, y6 = 0.f, y7 = 0.f;
    float z = 0.f;
    int j = q;
    for (; j + 4 < dc; j += 8) {
        unsigned wA = csr_se[start + j];
        unsigned wB = csr_se[start + j + 4];
        int sA = wA >> 15, sB = wB >> 15;
        float4 a0 = xa4[(size_t)sA * 2];
        float4 a1 = xa4[(size_t)sA * 2 + 1];
        float4 b0 = xa4[(size_t)sB * 2];
        float4 b1 = xa4[(size_t)sB * 2 + 1];
        float alsA = s16 + a0.x * ss0 + a0.y * ss4 + a0.z * ss1 + a0.w * ss5
                         + a1.x * ss2 + a1.y * ss6 + a1.z * ss3 + a1.w * ss7;
        float alsB = s16 + b0.x * ss0 + b0.y * ss4 + b0.z * ss1 + b0.w * ss5
                         + b1.x * ss2 + b1.y * ss6 + b1.z * ss3 + b1.w * ss7;
        float exA = __expf(lrelu(alsA + ald + (float)(wA & 32767u) * ce2));
        float exB = __expf(lrelu(alsB + ald + (float)(wB & 32767u) * ce2));
        z += exA + exB;
        y0 += exA * a0.x + exB * b0.x;
        y1 += exA * a0.y + exB * b0.y;
        y2 += exA * a0.z + exB * b0.z;
        y3 += exA * a0.w + exB * b0.w;
        y4 += exA * a1.x + exB * b1.x;
        y5 += exA * a1.y + exB * b1.y;
        y6 += exA * a1.z + exB * b1.z;
        y7 += exA * a1.w + exB * b1.w;
    }
    if (j < dc) {
        unsigned w = csr_se[start + j];
        int s = w >> 15;
        float4 a0 = xa4[(size_t)s * 2];
        float4 a1 = xa4[(size_t)s * 2 + 1];
        float als = s16 + a0.x * ss0 + a0.y * ss4 + a0.z * ss1 + a0.w * ss5
                        + a1.x * ss2 + a1.y * ss6 + a1.z * ss3 + a1.w * ss7;
        float ex = __expf(lrelu(als + ald + (float)(w & 32767u) * ce2));
        z += ex;
        y0 += ex * a0.x; y1 += ex * a0.y; y2 += ex * a0.z; y3 += ex * a0.w;
        y4 += ex * a1.x; y5 += ex * a1.y; y6 += ex * a1.z; y7 += ex * a1.w;
    }
    // reduce 9 accumulators across the 4-lane group (xor butterfly -> all lanes full)
    y0 += __shfl_xor(y0, 1, 64); y0 += __shfl_xor(y0, 2, 64);
    y1 += __shfl_xor(y1, 1, 64); y1 += __shfl_xor(y1, 2, 64);
    y2 += __shfl_xor(y2, 1, 64); y2 += __shfl_xor(y2, 2, 64);
    y3 += __shfl_xor(y3, 1, 64); y3 += __shfl_xor(y3, 2, 64);
    y4 += __shfl_xor(y4, 1, 64); y4 += __shfl_xor(y4, 2, 64);
    y5 += __shfl_xor(y5, 1, 64); y5 += __shfl_xor(y5, 2, 64);
    y6 += __shfl_xor(y6, 1, 64); y6 += __shfl_xor(y6, 2, 64);
    y7 += __shfl_xor(y7, 1, 64); y7 += __shfl_xor(y7, 2, 64);
    z += __shfl_xor(z, 1, 64); z += __shfl_xor(z, 2, 64);
    if (q == 0) {
        float inv = 1.f / (z + 1e-16f);
        __half2 p0 = __floats2half2_rn(y0 * inv, y1 * inv);
        __half2 p1 = __floats2half2_rn(y2 * inv, y3 * inv);
        __half2 p2 = __floats2half2_rn(y4 * inv, y5 * inv);
        __half2 p3 = __floats2half2_rn(y6 * inv, y7 * inv);
        uint4 o;
        o.x = *(unsigned*)&p0; o.y = *(unsigned*)&p1;
        o.z = *(unsigned*)&p2; o.w = *(unsigned*)&p3;
        Yh[n] = o;
        w0n[n] = z * inv;   // ~1, or 0 for empty segments (kills cW term)
    }
}

// ---------------- Edge regressor: thread/edge, scalar basis, PACKED fp32 math ---------
// k-loop over dim PAIRS with ext_vector float2 ops -> v_pk_fma_f32 (2 FMA/instr).
// Basis pairs are wave-uniform 8B loads (s_load_dwordx2). ccomb in V[672..735].
__global__ __launch_bounds__(256) void edge_kernel(
    const int* __restrict__ ei,
    const uint4* __restrict__ Yh, const float* __restrict__ w0n,
    const float* __restrict__ V,
    const float* __restrict__ Wr2,
    const float* __restrict__ br2, float* __restrict__ out, int E) {
    int e = blockIdx.x * 256 + threadIdx.x;
    if (e >= E) return;
    int s = ei[e], d = ei[E + e];
    uint4 ys = Yh[s], yd = Yh[d];
    float w0 = w0n[s] + w0n[d];
    float fs[8], fd[8], tt[8];
    h8_to_f(ys, fs);
    h8_to_f(yd, fd);
#pragma unroll
    for (int i = 0; i < 8; ++i) tt[i] = fs[i] + fd[i];
    v2f acc = {0.f, 0.f};
    v2f w0v = {w0, w0};
#pragma unroll
    for (int k = 0; k < 64; k += 2) {
        v2f g = w0v * (*(const v2f*)(V + 512 + k));
        g += *(const v2f*)(V + 672 + k);
        g += (v2f){tt[0], tt[0]} * (*(const v2f*)(V + k));
        g += (v2f){tt[1], tt[1]} * (*(const v2f*)(V + 256 + k));
        g += (v2f){tt[2], tt[2]} * (*(const v2f*)(V + 64 + k));
        g += (v2f){tt[3], tt[3]} * (*(const v2f*)(V + 320 + k));
        g += (v2f){tt[4], tt[4]} * (*(const v2f*)(V + 128 + k));
        g += (v2f){tt[5], tt[5]} * (*(const v2f*)(V + 384 + k));
        g += (v2f){tt[6], tt[6]} * (*(const v2f*)(V + 192 + k));
        g += (v2f){tt[7], tt[7]} * (*(const v2f*)(V + 448 + k));
        g = __builtin_elementwise_max(g, (v2f){0.f, 0.f});
        acc += g * (*(const v2f*)(Wr2 + k));
    }
    out[e] = acc.x + acc.y + br2[0];
}

extern "C" void kernel_launch(void* const* d_in, const int* in_sizes, int n_in,
                              void* d_out, int out_size, void* d_ws, size_t ws_size,
                              hipStream_t stream) {
    const float* x    = (const float*)d_in[0];
    const int*   ei   = (const int*)d_in[1];
    const float* ea   = (const float*)d_in[2];
    const float* W1   = (const float*)d_in[3];
    const float* We1  = (const float*)d_in[4];
    const float* as1  = (const float*)d_in[5];
    const float* ad1  = (const float*)d_in[6];
    const float* ae1  = (const float*)d_in[7];
    const float* b1   = (const float*)d_in[8];
    const float* W2   = (const float*)d_in[9];
    const float* We2  = (const float*)d_in[10];
    const float* as2  = (const float*)d_in[11];
    const float* ad2  = (const float*)d_in[12];
    const float* ae2  = (const float*)d_in[13];
    const float* b2   = (const float*)d_in[14];
    const float* Wr1  = (const float*)d_in[15];
    const float* br1  = (const float*)d_in[16];
    const float* Wr2  = (const float*)d_in[17];
    const float* br2  = (const float*)d_in[18];
    float* out = (float*)d_out;

    const int N = in_sizes[0] / 2;
    const int E = in_sizes[2];
    const int nbuck = (N + 511) >> 9;
    const size_t capE = (size_t)nbuck * BCAP;   // fixed-capacity CSR address space

    // workspace layout
    float* ws = (float*)d_ws;
    float*    rec   = ws;                            // N*8 {al_s1[4], x0, x1, pad, pad}
    float*    al_d1 = rec + (size_t)N * 8;           // N*4
    float*    al_s2 = al_d1 + (size_t)N * 4;         // N
    float*    al_d2 = al_s2 + N;                     // N
    float2*   XA    = (float2*)((((uintptr_t)(al_d2 + N)) + 31) & ~(uintptr_t)31); // N*4 float2 (32B aligned)
    float*    V     = (float*)((((uintptr_t)(XA + (size_t)N * 4)) + 15) & ~(uintptr_t)15); // 736 (pad 768)
    int*      deg   = (int*)(V + 768);               // N
    int*      offs  = deg + N;                       // N
    int*      bucket_cur  = offs + N;                // 256
    uint4*    Yh    = (uint4*)((((uintptr_t)(bucket_cur + 256)) + 15) & ~(uintptr_t)15); // N uint4
    float*    w0n   = (float*)(Yh + N);              // N
    uint2*    ebm   = (uint2*)((((uintptr_t)(w0n + N)) + 15) & ~(uintptr_t)15); // capE uint2
    unsigned* csr_se = (unsigned*)(ebm + capE);      // capE

    const int nb = (N + 255) / 256;

    prep1_kernel<<<nb, 256, 0, stream>>>(x, W1, as1, ad1, W2, b1, Wr1, b2, as2, ad2,
                                         br1, rec, al_d1, bucket_cur, V, N);
    binA_kernel<<<(E + TILE - 1) / TILE, 256, 0, stream>>>(ei, ea, bucket_cur, ebm,
                                                           E, nbuck);
    binB_kernel<<<nbuck, 256, 0, stream>>>(ebm, bucket_cur, deg, offs, csr_se, N);
    aggX_kernel<<<(4 * N + 255) / 256, 256, 0, stream>>>(csr_se, offs, deg,
                                                         rec, al_d1, We1, ae1, V,
                                                         XA, al_s2, al_d2, N);
    msg2y_kernel<<<(4 * N + 255) / 256, 256, 0, stream>>>(csr_se, offs, deg,
                                                          al_d2, We2, ae2, V, XA,
                                                          Yh, w0n, N);
    edge_kernel<<<(E + 255) / 256, 256, 0, stream>>>(ei, Yh, w0n, V, Wr2, br2,
                                                     out, E);
}